// Round 4
// baseline (699.326 us; speedup 1.0000x reference)
//
#include <hip/hip_runtime.h>

// GCN 2-layer: N=200000, E=12800000, features 2 -> 16 -> 2.
// R2: rank trick -- aggregate only 2-dim vectors (before W1 / after W2).
// R4-R8: counting sort by 256-node dst bucket + LDS aggregation; agg stuck at
//     ~150us: 12.8M fully-divergent 8B gathers = 1 L2 line request per edge,
//     ~7 cyc/lane/CU wall (per-CU outstanding-miss budget ~28 at ~200cyc L2
//     latency). MLP depth 1->4->16 changed nothing: request-COUNT bound.
// R9: composite sort key (dst>>12 [49 superbuckets], src>>11 [98 groups]) =
//     4802 bins. Each (sb, group) bin: ~2666 edges hitting a 16KB src slice
//     -> L1-resident -> ~10.4 edges/line -> L2 line requests drop 10x.
//     Accumulator = 4096 nodes x float2 = 32KB LDS per superbucket; cross-
//     segment merge via coalesced global f32 atomics into 1.6MB L2-resident
//     acc (no partial buffers). blockHist stored u16 (counts <= 12500, bin
//     totals <= ~2900). Entry: src(18b) | local_dst12 << 18. ws = 61.07MB
//     (< 61.61MB proven available). Node arrays overlay the dead blockHist.

constexpr int N_NODES = 200000;
constexpr int N_EDGES = 12800000;

// ---- composite sort geometry ----
constexpr int SB_SHIFT = 12;                          // 4096 nodes / superbucket
constexpr int NSB = (N_NODES + 4095) / 4096;          // 49
constexpr int SG_SHIFT = 11;                          // 2048 srcs / group
constexpr int NSG = (N_NODES + 2047) / 2048;          // 98
constexpr int NBIN = NSB * NSG;                       // 4802
constexpr int S2B = 1024;                             // sort blocks
constexpr int CH2 = N_EDGES / S2B;                    // 12500 exactly
constexpr int R19 = 19;                               // ceil(NBIN/256)
constexpr int DSEG = 24;                              // segments per superbucket
constexpr int ASEG = 24;

typedef unsigned uint32x4 __attribute__((ext_vector_type(4)));

// ---------------- sort phase ----------------

__global__ __launch_bounds__(256) void hist2_kernel(const int* __restrict__ src,
                                                    const int* __restrict__ dst,
                                                    unsigned short* __restrict__ bh16) {
    __shared__ unsigned h[NBIN];
    int t = threadIdx.x;
    for (int i = t; i < NBIN; i += 256) h[i] = 0;
    __syncthreads();
    int base = blockIdx.x * CH2;
    for (int e = base + t; e < base + CH2; e += 256) {
        unsigned d = (unsigned)dst[e];
        unsigned s = (unsigned)src[e];
        atomicAdd(&h[(d >> SB_SHIFT) * NSG + (s >> SG_SHIFT)], 1u);
    }
    __syncthreads();
    unsigned short* row = bh16 + (size_t)blockIdx.x * NBIN;
    for (int i = t; i < NBIN; i += 256) row[i] = (unsigned short)h[i];
}

// Column scans of bh16[S2B][NBIN]: block g handles 16 consecutive bins.
// thread: bin = t&15, chunk = t>>4 (16 chunks x 64 rows). Converts raw counts
// to exclusive-over-blocks prefixes (u16) and emits binTotal (u32).
__global__ __launch_bounds__(256) void scan2_kernel(unsigned short* __restrict__ bh16,
                                                    unsigned* __restrict__ binTotal) {
    __shared__ unsigned psum[16][17];
    int t = threadIdx.x;
    int binL = t & 15, chunk = t >> 4;
    int bin = blockIdx.x * 16 + binL;
    bool ok = bin < NBIN;
    unsigned s = 0;
    if (ok) {
        for (int r = chunk * 64; r < chunk * 64 + 64; ++r)
            s += bh16[(size_t)r * NBIN + bin];
    }
    psum[chunk][binL] = s;
    __syncthreads();
    if (chunk == 0 && ok) {
        unsigned run = 0;
        for (int c = 0; c < 16; ++c) { unsigned tmp = psum[c][binL]; psum[c][binL] = run; run += tmp; }
        binTotal[bin] = run;
    }
    __syncthreads();
    if (ok) {
        unsigned run = psum[chunk][binL];
        for (int r = chunk * 64; r < chunk * 64 + 64; ++r) {
            size_t idx = (size_t)r * NBIN + bin;
            unsigned tmp = bh16[idx];
            bh16[idx] = (unsigned short)run;
            run += tmp;
        }
    }
}

// Single block: exclusive scan of 4802 bin totals -> binStart[0..NBIN].
__global__ __launch_bounds__(256) void scan_bins2_kernel(const unsigned* __restrict__ binTotal,
                                                         unsigned* __restrict__ binStart) {
    __shared__ unsigned sh[256];
    int t = threadIdx.x;
    unsigned v[R19], run = 0;
#pragma unroll
    for (int j = 0; j < R19; j++) { int idx = R19 * t + j; v[j] = (idx < NBIN) ? binTotal[idx] : 0u; }
#pragma unroll
    for (int j = 0; j < R19; j++) { unsigned tmp = v[j]; v[j] = run; run += tmp; }
    sh[t] = run;
    __syncthreads();
    for (int off = 1; off < 256; off <<= 1) {
        unsigned add = (t >= off) ? sh[t - off] : 0u;
        __syncthreads();
        sh[t] += add;
        __syncthreads();
    }
    unsigned excl = sh[t] - run;
#pragma unroll
    for (int j = 0; j < R19; j++) { int idx = R19 * t + j; if (idx < NBIN) binStart[idx] = excl + v[j]; }
    if (t == 255) binStart[NBIN] = sh[255];
}

// Block-local counting sort in LDS by composite bin, in-order coalesced
// copy-out. Per-block counts reconstructed from scanned bh16 rows (R8 trick).
__global__ __launch_bounds__(256) void scatter2_kernel(const int* __restrict__ src,
                                                       const int* __restrict__ dst,
                                                       const unsigned short* __restrict__ bh16,
                                                       const unsigned* __restrict__ binTotal,
                                                       const unsigned* __restrict__ binStart,
                                                       unsigned* __restrict__ sorted) {
    __shared__ unsigned s_cur[NBIN];          // local cursor, then reused as base
    __shared__ unsigned ssum[256];
    __shared__ unsigned ent[CH2];
    __shared__ unsigned short bkk[CH2];

    int t = threadIdx.x;
    int k = blockIdx.x;
    int base = k * CH2;
    const unsigned short* row  = bh16 + (size_t)k * NBIN;
    const unsigned short* rowN = bh16 + (size_t)(k + 1) * NBIN;
    bool last = (k == S2B - 1);

    unsigned v[R19], g0[R19], run = 0;
#pragma unroll
    for (int j = 0; j < R19; j++) {
        int idx = R19 * t + j;
        if (idx < NBIN) {
            unsigned r0 = row[idx];
            unsigned r1 = last ? binTotal[idx] : (unsigned)rowN[idx];
            g0[j] = r0;
            v[j]  = r1 - r0;                  // this block's count for bin idx
        } else { g0[j] = 0; v[j] = 0; }
    }
#pragma unroll
    for (int j = 0; j < R19; j++) { unsigned tmp = v[j]; v[j] = run; run += tmp; }
    ssum[t] = run;
    __syncthreads();
    for (int off = 1; off < 256; off <<= 1) {
        unsigned add = (t >= off) ? ssum[t - off] : 0u;
        __syncthreads();
        ssum[t] += add;
        __syncthreads();
    }
    unsigned excl = ssum[t] - run;
#pragma unroll
    for (int j = 0; j < R19; j++) {
        int idx = R19 * t + j;
        if (idx < NBIN) s_cur[idx] = excl + v[j];   // local start of bin idx
    }
    __syncthreads();

    for (int e = base + t; e < base + CH2; e += 256) {
        unsigned d = (unsigned)dst[e];
        unsigned s = (unsigned)src[e];
        unsigned b = (d >> SB_SHIFT) * NSG + (s >> SG_SHIFT);
        unsigned lpos = atomicAdd(&s_cur[b], 1u);
        ent[lpos] = s | ((d & 4095u) << 18);
        bkk[lpos] = (unsigned short)b;
    }
    __syncthreads();

    // Reuse s_cur as signed base: global = binStart + prefix - localStart.
#pragma unroll
    for (int j = 0; j < R19; j++) {
        int idx = R19 * t + j;
        if (idx < NBIN) {
            unsigned st = excl + v[j];
            s_cur[idx] = (unsigned)((int)(binStart[idx] + g0[j]) - (int)st);
        }
    }
    __syncthreads();

    for (int i = t; i < CH2; i += 256) {
        unsigned b = bkk[i];
        sorted[(int)s_cur[b] + i] = ent[i];
    }
}

// ---------------- GCN phase ----------------
// blocks = NSB*SEG: sb = blockIdx.x / SEG, s = blockIdx.x % SEG. Superbucket
// edge range from binStart[sb*NSG .. (sb+1)*NSG]. Edges grouped by src>>11
// inside -> gathers hit a 16KB L1-resident slice.

__global__ __launch_bounds__(256) void zero_kernel(unsigned* __restrict__ p, int n) {
    int i = blockIdx.x * 256 + threadIdx.x;
    if (i < n) p[i] = 0u;
}

__global__ __launch_bounds__(256) void deg2_kernel(const unsigned* __restrict__ sorted,
                                                   const unsigned* __restrict__ binStart,
                                                   unsigned* __restrict__ deg) {
    __shared__ unsigned cnt[4096];
    int t = threadIdx.x;
    for (int i = t; i < 4096; i += 256) cnt[i] = 0;
    __syncthreads();
    int sb = blockIdx.x / DSEG, s = blockIdx.x % DSEG;
    int s0 = binStart[sb * NSG];
    int len = binStart[(sb + 1) * NSG] - s0;
    int e0 = s0 + (len * s) / DSEG;
    int e1 = s0 + (len * (s + 1)) / DSEG;

    int e0a = (e0 + 3) & ~3;
    if (e0a > e1) e0a = e1;
    if (t < e0a - e0) {
        unsigned w = sorted[e0 + t];
        atomicAdd(&cnt[(w >> 18) & 4095u], 1u);
    }
    int nq = (e1 - e0a) >> 2;
    const uint32x4* q4 = (const uint32x4*)(sorted + e0a);
    int q = t;
    for (; q + 768 < nq; q += 1024) {
        uint32x4 w0 = q4[q];
        uint32x4 w1 = q4[q + 256];
        uint32x4 w2 = q4[q + 512];
        uint32x4 w3 = q4[q + 768];
#pragma unroll
        for (int j = 0; j < 4; j++) atomicAdd(&cnt[(w0[j] >> 18) & 4095u], 1u);
#pragma unroll
        for (int j = 0; j < 4; j++) atomicAdd(&cnt[(w1[j] >> 18) & 4095u], 1u);
#pragma unroll
        for (int j = 0; j < 4; j++) atomicAdd(&cnt[(w2[j] >> 18) & 4095u], 1u);
#pragma unroll
        for (int j = 0; j < 4; j++) atomicAdd(&cnt[(w3[j] >> 18) & 4095u], 1u);
    }
    for (; q < nq; q += 256) {
        uint32x4 w0 = q4[q];
#pragma unroll
        for (int j = 0; j < 4; j++) atomicAdd(&cnt[(w0[j] >> 18) & 4095u], 1u);
    }
    int tail0 = e0a + (nq << 2);
    if (t < e1 - tail0) {
        unsigned w = sorted[tail0 + t];
        atomicAdd(&cnt[(w >> 18) & 4095u], 1u);
    }
    __syncthreads();
    int nb = sb << SB_SHIFT;
    for (int i = t; i < 4096; i += 256) {
        int node = nb + i;
        if (node < N_NODES && cnt[i]) atomicAdd(&deg[node], cnt[i]);
    }
}

__global__ __launch_bounds__(256) void node1n_kernel(const float2* __restrict__ x,
                                                     unsigned* __restrict__ degdinv,
                                                     float2* __restrict__ u) {
    int i = blockIdx.x * 256 + threadIdx.x;
    if (i >= N_NODES) return;
    unsigned c = degdinv[i] + 1u;  // +1 self loop
    float di = rsqrtf((float)c);
    ((float*)degdinv)[i] = di;     // in-place u32 -> f32, same slot
    float2 xi = x[i];
    u[i] = make_float2(di * xi.x, di * xi.y);
}

__device__ __forceinline__ void agg_gather(const float2* __restrict__ table,
                                           const uint32x4 w, float2 v[4]) {
    v[0] = table[w[0] & 0x3FFFFu];
    v[1] = table[w[1] & 0x3FFFFu];
    v[2] = table[w[2] & 0x3FFFFu];
    v[3] = table[w[3] & 0x3FFFFu];
}

__device__ __forceinline__ void agg_accum(float* ax, float* ay,
                                          const uint32x4 w, const float2 v[4]) {
#pragma unroll
    for (int j = 0; j < 4; j++) {
        unsigned l = (w[j] >> 18) & 4095u;
        atomicAdd(&ax[l], v[j].x);
        atomicAdd(&ay[l], v[j].y);
    }
}

__global__ __launch_bounds__(256) void agg2_kernel(const unsigned* __restrict__ sorted,
                                                   const unsigned* __restrict__ binStart,
                                                   const float2* __restrict__ table,
                                                   float* __restrict__ acc) {
    __shared__ float ax[4096], ay[4096];
    int t = threadIdx.x;
    for (int i = t; i < 4096; i += 256) { ax[i] = 0.f; ay[i] = 0.f; }
    __syncthreads();
    int sb = blockIdx.x / ASEG, s = blockIdx.x % ASEG;
    int s0 = binStart[sb * NSG];
    int len = binStart[(sb + 1) * NSG] - s0;
    int e0 = s0 + (len * s) / ASEG;
    int e1 = s0 + (len * (s + 1)) / ASEG;

    int e0a = (e0 + 3) & ~3;
    if (e0a > e1) e0a = e1;
    if (t < e0a - e0) {
        unsigned w = sorted[e0 + t];
        float2 v = table[w & 0x3FFFFu];
        unsigned l = (w >> 18) & 4095u;
        atomicAdd(&ax[l], v.x);
        atomicAdd(&ay[l], v.y);
    }
    int nq = (e1 - e0a) >> 2;
    const uint32x4* q4 = (const uint32x4*)(sorted + e0a);
    int q = t;
    for (; q + 768 < nq; q += 1024) {
        uint32x4 w0 = q4[q];
        uint32x4 w1 = q4[q + 256];
        uint32x4 w2 = q4[q + 512];
        uint32x4 w3 = q4[q + 768];
        float2 v0[4], v1[4], v2[4], v3[4];
        agg_gather(table, w0, v0);
        agg_gather(table, w1, v1);
        agg_gather(table, w2, v2);
        agg_gather(table, w3, v3);
        agg_accum(ax, ay, w0, v0);
        agg_accum(ax, ay, w1, v1);
        agg_accum(ax, ay, w2, v2);
        agg_accum(ax, ay, w3, v3);
    }
    for (; q < nq; q += 256) {
        uint32x4 w0 = q4[q];
        float2 v0[4];
        agg_gather(table, w0, v0);
        agg_accum(ax, ay, w0, v0);
    }
    int tail0 = e0a + (nq << 2);
    if (t < e1 - tail0) {
        unsigned w = sorted[tail0 + t];
        float2 v = table[w & 0x3FFFFu];
        unsigned l = (w >> 18) & 4095u;
        atomicAdd(&ax[l], v.x);
        atomicAdd(&ay[l], v.y);
    }
    __syncthreads();
    // Coalesced flush into L2-resident global accumulator.
    int nb = sb << SB_SHIFT;
    for (int i = t; i < 4096; i += 256) {
        int node = nb + i;
        if (node < N_NODES) {
            unsafeAtomicAdd(&acc[2 * node],     ax[i]);
            unsafeAtomicAdd(&acc[2 * node + 1], ay[i]);
        }
    }
}

__global__ __launch_bounds__(256) void node2n_kernel(const float2* __restrict__ acc,
                                                     float2* __restrict__ u,   // in: u, out: g2
                                                     const float* __restrict__ W1,
                                                     const float* __restrict__ b1,
                                                     const float* __restrict__ W2,
                                                     const float* __restrict__ dinv) {
    int i = blockIdx.x * 256 + threadIdx.x;
    if (i >= N_NODES) return;
    float di = dinv[i];
    float2 a = acc[i], uu = u[i];
    float c0 = di * (a.x + uu.x);
    float c1 = di * (a.y + uu.y);
    float a0 = 0.f, a1 = 0.f;
#pragma unroll
    for (int f = 0; f < 16; f++) {
        float o = fmaxf(c0 * W1[f] + c1 * W1[16 + f] + b1[f], 0.f);  // W1 (2,16)
        a0 += o * W2[2 * f];                                         // W2 (16,2)
        a1 += o * W2[2 * f + 1];
    }
    u[i] = make_float2(di * a0, di * a1);   // g2, same slot
}

__global__ __launch_bounds__(256) void node3n_kernel(const float2* __restrict__ acc,
                                                     const float2* __restrict__ g2,
                                                     const float* __restrict__ b2,
                                                     const float* __restrict__ dinv,
                                                     float2* __restrict__ out) {
    int i = blockIdx.x * 256 + threadIdx.x;
    if (i >= N_NODES) return;
    float di = dinv[i];
    float2 a = acc[i], g = g2[i];
    out[i] = make_float2(di * (a.x + g.x) + b2[0],
                         di * (a.y + g.y) + b2[1]);
}

// ---------------- fallback path (R2-style, needs only 8 MB ws) ----------------

__global__ __launch_bounds__(256) void fb_deg(const int* __restrict__ dst, int* __restrict__ degi) {
    int e = blockIdx.x * 256 + threadIdx.x;
    if (e < N_EDGES) atomicAdd(&degi[dst[e]], 1);
}
__global__ __launch_bounds__(256) void fb_node1(const float* __restrict__ x, const int* __restrict__ degi,
                                                float* __restrict__ dinv, float2* __restrict__ u) {
    int i = blockIdx.x * 256 + threadIdx.x;
    if (i >= N_NODES) return;
    float di = rsqrtf((float)(degi[i] + 1));
    dinv[i] = di;
    float2 xi = ((const float2*)x)[i];
    u[i] = make_float2(di * xi.x, di * xi.y);
}
__global__ __launch_bounds__(256) void fb_agg(const int* __restrict__ src, const int* __restrict__ dst,
                                              const float2* __restrict__ table, float* __restrict__ acc) {
    int e = blockIdx.x * 256 + threadIdx.x;
    if (e >= N_EDGES) return;
    float2 v = table[src[e]];
    size_t d = dst[e];
    unsafeAtomicAdd(&acc[2 * d], v.x);
    unsafeAtomicAdd(&acc[2 * d + 1], v.y);
}
__global__ __launch_bounds__(256) void fb_node2(const float2* __restrict__ u, const float2* __restrict__ A1,
                                                const float* __restrict__ W1, const float* __restrict__ b1,
                                                const float* __restrict__ W2, const float* __restrict__ dinv,
                                                float2* __restrict__ g2) {
    int i = blockIdx.x * 256 + threadIdx.x;
    if (i >= N_NODES) return;
    float di = dinv[i];
    float2 a = A1[i], uu = u[i];
    float c0 = di * (a.x + uu.x), c1 = di * (a.y + uu.y);
    float a0 = 0.f, a1 = 0.f;
#pragma unroll
    for (int f = 0; f < 16; f++) {
        float o = fmaxf(c0 * W1[f] + c1 * W1[16 + f] + b1[f], 0.f);
        a0 += o * W2[2 * f];
        a1 += o * W2[2 * f + 1];
    }
    g2[i] = make_float2(di * a0, di * a1);
}
__global__ __launch_bounds__(256) void fb_node3(const float2* __restrict__ g2, const float2* __restrict__ A2,
                                                const float* __restrict__ b2, const float* __restrict__ dinv,
                                                float2* __restrict__ out) {
    int i = blockIdx.x * 256 + threadIdx.x;
    if (i >= N_NODES) return;
    float di = dinv[i];
    float2 a = A2[i], g = g2[i];
    out[i] = make_float2(di * (a.x + g.x) + b2[0], di * (a.y + g.y) + b2[1]);
}

// ---------------- launcher ----------------

extern "C" void kernel_launch(void* const* d_in, const int* in_sizes, int n_in,
                              void* d_out, int out_size, void* d_ws, size_t ws_size,
                              hipStream_t stream) {
    const float* x  = (const float*)d_in[0];
    const float* W1 = (const float*)d_in[1];
    const float* b1 = (const float*)d_in[2];
    const float* W2 = (const float*)d_in[3];
    const float* b2 = (const float*)d_in[4];
    const int* ei   = (const int*)d_in[5];   // (2,E): row 0 = src, row 1 = dst
    const int* src = ei;
    const int* dst = ei + N_EDGES;
    float2* out = (float2*)d_out;

    // ws layout (4B words), total 61.07 MB (< 61.61 MB proven available):
    //   sorted   [E]                         12,800,000
    //   bh16     [S2B*NBIN] u16               2,458,624 words -- dead after
    //       scatter2; overlaid by: deg/dinv [200,000] + acc [400,000]
    //       + u/g2 [400,000] = 1,000,000 words (fits)
    //   binTotal [NBIN]                            4,802
    //   binStart [NBIN+1] (+pad)                   4,806
    const size_t need = ((size_t)N_EDGES + (size_t)S2B * NBIN / 2 + NBIN + 4806) * 4;

    if (ws_size >= need) {
        unsigned* sorted        = (unsigned*)d_ws;
        unsigned short* bh16    = (unsigned short*)(sorted + N_EDGES);
        unsigned* deg           = (unsigned*)bh16;          // overlay (post-scatter)
        float*    dinv          = (float*)deg;              // alias, same slots
        float*    acc           = (float*)(deg + N_NODES);  // 400,000 words
        float2*   u             = (float2*)(acc + 2 * (size_t)N_NODES);
        unsigned* binTotal      = (unsigned*)(bh16 + (size_t)S2B * NBIN);
        unsigned* binStart      = binTotal + NBIN;

        hist2_kernel<<<S2B, 256, 0, stream>>>(src, dst, bh16);
        scan2_kernel<<<(NBIN + 15) / 16, 256, 0, stream>>>(bh16, binTotal);
        scan_bins2_kernel<<<1, 256, 0, stream>>>(binTotal, binStart);
        scatter2_kernel<<<S2B, 256, 0, stream>>>(src, dst, bh16, binTotal, binStart, sorted);
        // blockHist region now dead -> zero deg + acc overlay (600,000 words)
        zero_kernel<<<(600000 + 255) / 256, 256, 0, stream>>>(deg, 600000);
        deg2_kernel<<<NSB * DSEG, 256, 0, stream>>>(sorted, binStart, deg);
        node1n_kernel<<<(N_NODES + 255) / 256, 256, 0, stream>>>((const float2*)x, deg, u);
        agg2_kernel<<<NSB * ASEG, 256, 0, stream>>>(sorted, binStart, u, acc);
        node2n_kernel<<<(N_NODES + 255) / 256, 256, 0, stream>>>((const float2*)acc, u, W1, b1, W2, dinv);
        zero_kernel<<<(400000 + 255) / 256, 256, 0, stream>>>((unsigned*)acc, 400000);
        agg2_kernel<<<NSB * ASEG, 256, 0, stream>>>(sorted, binStart, u, acc);
        node3n_kernel<<<(N_NODES + 255) / 256, 256, 0, stream>>>((const float2*)acc, u, b2, dinv, out);
    } else {
        // R2-style fallback (8 MB ws): global atomics, ~3.1 ms.
        float* ws = (float*)d_ws;
        int*   degi = (int*)ws;
        float* A1   = ws + N_NODES;
        float* A2   = A1 + 2 * (size_t)N_NODES;
        float* dinvF = A2 + 2 * (size_t)N_NODES;
        float2* uF  = (float2*)(dinvF + N_NODES);
        float2* g2F = uF + N_NODES;
        constexpr int EB = (N_EDGES + 255) / 256;
        constexpr int NB = (N_NODES + 255) / 256;
        (void)hipMemsetAsync(degi, 0, 5 * (size_t)N_NODES * sizeof(float), stream);
        fb_deg<<<EB, 256, 0, stream>>>(dst, degi);
        fb_node1<<<NB, 256, 0, stream>>>(x, degi, dinvF, uF);
        fb_agg<<<EB, 256, 0, stream>>>(src, dst, uF, A1);
        fb_node2<<<NB, 256, 0, stream>>>(uF, (const float2*)A1, W1, b1, W2, dinvF, g2F);
        fb_agg<<<EB, 256, 0, stream>>>(src, dst, g2F, A2);
        fb_node3<<<NB, 256, 0, stream>>>(g2F, (const float2*)A2, b2, dinvF, out);
    }
}